// Round 7
// baseline (545.740 us; speedup 1.0000x reference)
//
#include <hip/hip_runtime.h>

#define NB 2
#define CIN 3
#define HH 512
#define WW 512
#define C2 64
#define HM 504   // mode-pool output size

typedef float v2f  __attribute__((ext_vector_type(2)));
typedef float v2fu __attribute__((ext_vector_type(2), aligned(4)));

// ---------------- K2: quantize (inline) + mode pool 11x11 -> u8 [2,3,504,504] ----------------
__global__ __launch_bounds__(256) void k_mode(const float* __restrict__ x,
                                              unsigned char* __restrict__ hmode) {
  __shared__ unsigned char tile[26 * 26];
  int bc  = blockIdx.z;
  int ty0 = blockIdx.y * 16, tx0 = blockIdx.x * 16;
  const float* src = x + (size_t)bc * HH * WW;
  for (int i = threadIdx.x; i < 26 * 26; i += 256) {
    int r = i / 26, cl = i % 26;
    int Y = ty0 + r, X = tx0 + cl;      // padded coords (pad=1)
    unsigned char v = 0;
    if (Y >= 1 && Y <= HH && X >= 1 && X <= WW) {
      float val = src[(Y - 1) * WW + (X - 1)];
      float q = rintf((val * 255.0f) / 16.0f);   // matches jnp.round(x*255/16), RNE
      q = fminf(fmaxf(q, 0.0f), 16.0f);
      v = (unsigned char)(int)q;
    }
    tile[i] = v;
  }
  __syncthreads();
  int ty = threadIdx.x >> 4, tx = threadIdx.x & 15;
  int oy = ty0 + ty, ox = tx0 + tx;
  if (oy >= HM || ox >= HM) return;
  unsigned long long w0 = 0, w1 = 0, w2 = 0;
  for (int dy = 0; dy < 11; dy++) {
    #pragma unroll
    for (int dx = 0; dx < 11; dx++) {
      int b = tile[(ty + dy) * 26 + tx + dx];
      unsigned long long inc = 1ull << ((b & 7) * 8);
      if (b < 8) w0 += inc;
      else if (b < 16) w1 += inc;
      else w2 += inc;
    }
  }
  int best = -1, bestb = 0;
  #pragma unroll
  for (int b = 0; b < 17; b++) {
    int cnt;
    if (b < 8)       cnt = (int)((w0 >> (b * 8)) & 0xff);
    else if (b < 16) cnt = (int)((w1 >> ((b - 8) * 8)) & 0xff);
    else             cnt = (int)(w2 & 0xff);
    if (cnt > best) { best = cnt; bestb = b; }   // strict > keeps lowest bin on tie
  }
  hmode[bc * HM * HM + oy * HM + ox] = (unsigned char)bestb;
}

// ---------------- K3: fused conv1+maxleaky + grouped conv2 + minleaky + downgrade ----------------
__global__ __launch_bounds__(256) void k_prepare(const unsigned char* __restrict__ hmode,
                                                 const float* __restrict__ w1,
                                                 const float* __restrict__ b1,
                                                 const float* __restrict__ w2,
                                                 const float* __restrict__ b2,
                                                 const float* __restrict__ down_k,
                                                 const float* __restrict__ down_b,
                                                 float* __restrict__ d1) {
  int bc = blockIdx.y;
  int b  = bc >> 6;
  int c  = bc & 63;
  int pix = blockIdx.x * 256 + threadIdx.x;
  if (pix >= 168 * 168) return;
  int oy = pix / 168, ox = pix % 168;
  int c0 = (c >> 1) << 1;
  float w1a0 = w1[c0 * 3], w1a1 = w1[c0 * 3 + 1], w1a2 = w1[c0 * 3 + 2], b1a = b1[c0];
  float w1b0 = w1[(c0 + 1) * 3], w1b1 = w1[(c0 + 1) * 3 + 1], w1b2 = w1[(c0 + 1) * 3 + 2], b1b = b1[c0 + 1];
  float w2a = w2[c * 2], w2b = w2[c * 2 + 1], b2c = b2[c];
  float kb = *down_b;
  const unsigned char* h0p = hmode + (b * 3 + 0) * HM * HM;
  const unsigned char* h1p = hmode + (b * 3 + 1) * HM * HM;
  const unsigned char* h2p = hmode + (b * 3 + 2) * HM * HM;
  float acc = 0.0f;
  #pragma unroll
  for (int ky = 0; ky < 3; ky++) {
    int y = 3 * oy - 1 + ky;
    if (y < 0 || y >= HM) continue;
    #pragma unroll
    for (int kx = 0; kx < 3; kx++) {
      int xx = 3 * ox - 1 + kx;
      if (xx < 0 || xx >= HM) continue;
      int o = y * HM + xx;
      float hh0 = h0p[o] * (1.0f / 16.0f);
      float hh1 = h1p[o] * (1.0f / 16.0f);
      float hh2 = h2p[o] * (1.0f / 16.0f);
      float a0 = w1a0 * hh0 + w1a1 * hh1 + w1a2 * hh2 + b1a;
      float a1 = w1b0 * hh0 + w1b1 * hh1 + w1b2 * hh2 + b1b;
      a0 = (a0 <= 0.1f) ? a0 : 0.1f + 0.01f * (a0 - 0.1f);
      a1 = (a1 <= 0.1f) ? a1 : 0.1f + 0.01f * (a1 - 0.1f);
      float v = w2a * a0 + w2b * a1 + b2c;
      v = (v >= 0.1f) ? v : 0.1f + 0.01f * (v - 0.1f);
      acc += down_k[ky * 3 + kx] * v;
    }
  }
  float r = acc + kb;
  r = (r >= 0.0f) ? r : 0.01f * r;
  d1[bc * 168 * 168 + pix] = r;
}

// ---------------- K4: generic downgrade (3x3 s3 p1 shared) + leaky ----------------
__global__ __launch_bounds__(256) void k_down(const float* __restrict__ din,
                                              float* __restrict__ dout,
                                              const float* __restrict__ down_k,
                                              const float* __restrict__ down_b,
                                              int S, int So) {
  int bc = blockIdx.y;
  int pix = blockIdx.x * 256 + threadIdx.x;
  if (pix >= So * So) return;
  int oy = pix / So, ox = pix % So;
  const float* p = din + bc * S * S;
  float acc = 0.0f;
  #pragma unroll
  for (int ky = 0; ky < 3; ky++) {
    int y = 3 * oy - 1 + ky;
    if (y < 0 || y >= S) continue;
    #pragma unroll
    for (int kx = 0; kx < 3; kx++) {
      int xx = 3 * ox - 1 + kx;
      if (xx < 0 || xx >= S) continue;
      acc += down_k[ky * 3 + kx] * p[y * S + xx];
    }
  }
  float r = acc + *down_b;
  r = (r >= 0.0f) ? r : 0.01f * r;
  dout[bc * So * So + pix] = r;
}

// ---------------- K_lut: packed bilinear LUT {asfloat(y0), w} per level/coord ----------------
__global__ __launch_bounds__(256) void k_lut(float2* __restrict__ lutpk) {
  int idx = blockIdx.x * 256 + threadIdx.x;   // 5*512
  if (idx >= 5 * 512) return;
  int lvl = idx >> 9, Y = idx & 511;
  const int Ls[5] = {168, 56, 19, 7, 3};
  int L = Ls[lvl];
  float f = (Y + 0.5f) * ((float)L / 512.0f) - 0.5f;
  f = fminf(fmaxf(f, 0.0f), (float)(L - 1));
  int y0 = (int)f;
  float w = f - (float)y0;
  lutpk[idx] = make_float2(__int_as_float(y0), w);
}

// ---------------- K5: composite 5-level resize+conv+BN+leaky+sum, v3 ----------------
// v3: xrow uses a 4-float pad every 32 cols (XI(c) = c + ((c>>5)<<2), row stride
// 148). Lane i's b128 at dword 8i+4*(i>>2) -> 16 lanes hit banks
// {0,8,16,24,4,12,20,28}x2 = 2-way (free) instead of v2's 4-way stride-8
// pattern (1.74e7 conflict cycles). Pad is 4 dwords so 16B alignment holds and
// any aligned 4-col window stays inside one 32-block (B = A+4 always legal).
#define XI(cc) ((cc) + ((((cc) >> 5)) << 2))
#define XSTR 148
__global__ __launch_bounds__(256, 4) void k_score(const float* __restrict__ d1,
                                                  const float* __restrict__ d2,
                                                  const float* __restrict__ d3,
                                                  const float* __restrict__ d4,
                                                  const float* __restrict__ d5,
                                                  const float2* __restrict__ lutpk,
                                                  const float* __restrict__ interp_k,
                                                  const float* __restrict__ interp_b,
                                                  const float* __restrict__ i_gamma,
                                                  const float* __restrict__ i_beta,
                                                  const float* __restrict__ i_mean,
                                                  const float* __restrict__ i_var,
                                                  float* __restrict__ score) {
  __shared__ float xrow[24 * XSTR];    // [r][XI(xx)]
  __shared__ float kap[64 * 36];       // [y][rr*8 + kx], 5 used per slot
  __shared__ int   abase[64];          // a0base(y) - r0

  int bc = blockIdx.y;
  int c  = bc & 63;
  int tile = blockIdx.x;               // 32 tiles: 8 y-tiles x 4 x-tiles
  int tyi = tile >> 2, txi = tile & 3;
  int ty0 = tyi * 64, tx0 = txi * 128;
  float K[25];
  #pragma unroll
  for (int i = 0; i < 25; i++)
    K[i] = __int_as_float(__builtin_amdgcn_readfirstlane(__float_as_int(interp_k[i])));
  float ib  = __int_as_float(__builtin_amdgcn_readfirstlane(__float_as_int(*interp_b)));
  float isc = i_gamma[c] * rsqrtf(i_var[c] + 1e-5f);
  float ibe = i_beta[c] - i_mean[c] * isc;
  int tid = threadIdx.x;
  int oyl = (tid >> 4) << 2, oxl = (tid & 15) << 3;  // 4x8 px per thread
  const int pA = XI(oxl);              // col oxl   (A; B = pA+4)
  const int pC = XI(oxl + 8);          // col oxl+8 (Cx)
  float acc[4][8];
  #pragma unroll
  for (int i = 0; i < 4; i++)
    #pragma unroll
    for (int j = 0; j < 8; j++) acc[i][j] = 0.0f;

  const float* dls[5] = {d1, d2, d3, d4, d5};
  const int Ls[5]  = {168, 56, 19, 7, 3};
  const int RLs[5] = {24, 10, 5, 3, 3};

  auto fillLevel = [&](int l) {
    int L = Ls[l], RR = RLs[l];
    const float* dp = dls[l] + bc * L * L;
    const float2* lp = lutpk + (l << 9);
    int Ylo = max(ty0 - 2, 0);
    int r0 = __float_as_int(lp[Ylo].x);
    // kappa: thread tid -> (y = tid>>2, rrel = tid&3)
    {
      int y = tid >> 2, rr = tid & 3;
      int Y = ty0 + y;
      float kv0 = 0.0f, kv1 = 0.0f, kv2 = 0.0f, kv3 = 0.0f, kv4 = 0.0f;
      int ab = -1;
      #pragma unroll
      for (int ky = 0; ky < 5; ky++) {
        int yy = Y + ky - 2;
        if (yy >= 0 && yy < 512) {
          float2 pk = lp[yy];
          int a0 = __float_as_int(pk.x);
          float wv = pk.y;
          if (ab < 0) ab = a0;           // first valid ky has the min a0 (monotone)
          float cf = 0.0f;
          if (a0 - ab == rr)     cf += 1.0f - wv;
          if (a0 + 1 - ab == rr) cf += wv;
          kv0 += cf * K[ky * 5 + 0];
          kv1 += cf * K[ky * 5 + 1];
          kv2 += cf * K[ky * 5 + 2];
          kv3 += cf * K[ky * 5 + 3];
          kv4 += cf * K[ky * 5 + 4];
        }
      }
      float* kp = &kap[y * 36 + rr * 8];
      kp[0] = kv0; kp[1] = kv1; kp[2] = kv2; kp[3] = kv3; kp[4] = kv4;
      if (rr == 0) abase[y] = ab - r0;
    }
    // xrow: x-upsample coarse rows, zero outside image columns
    for (int i = tid; i < RR * 132; i += 256) {
      int r = i / 132, xx = i - r * 132;
      int X = tx0 - 2 + xx;
      float v = 0.0f;
      if (X >= 0 && X < 512) {
        float2 pk = lp[X];
        int ix = __float_as_int(pk.x);
        float wx = pk.y;
        int gr = min(r0 + r, L - 1);
        const float* rp = dp + gr * L + ix;
        float v0 = rp[0], v1 = rp[1];    // v1 unused when wx==0 (clamp)
        v = v0 + wx * (v1 - v0);
      }
      xrow[r * XSTR + XI(xx)] = v;
    }
  };

  auto convAcc = [&](int rspan, int rlim) {
    #pragma unroll
    for (int i = 0; i < 4; i++) {
      int y = oyl + i;
      int ab = abase[y];
      float t[8];
      #pragma unroll
      for (int j = 0; j < 8; j++) t[j] = 0.0f;
      for (int rr = 0; rr < rspan; rr++) {
        int row = min(ab + rr, rlim);    // kappa==0 whenever clamp engages
        const float* xp = &xrow[row * XSTR];
        float4 A = *(const float4*)(xp + pA);
        float4 B = *(const float4*)(xp + pA + 4);
        float4 Cx = *(const float4*)(xp + pC);
        const float* kp = &kap[y * 36 + rr * 8];
        float4 kk = *(const float4*)kp;
        float k4v = kp[4];
        float wnd[12] = {A.x, A.y, A.z, A.w, B.x, B.y, B.z, B.w, Cx.x, Cx.y, Cx.z, Cx.w};
        #pragma unroll
        for (int j = 0; j < 8; j++)
          t[j] += kk.x * wnd[j] + kk.y * wnd[j + 1] + kk.z * wnd[j + 2] +
                  kk.w * wnd[j + 3] + k4v * wnd[j + 4];
      }
      #pragma unroll
      for (int j = 0; j < 8; j++) {
        float v = (t[j] + ib) * isc + ibe;
        v = (v >= 0.0f) ? v : 0.01f * v;
        acc[i][j] += v;
      }
    }
  };

  #pragma unroll 1
  for (int l = 0; l < 5; l++) {
    if (l) __syncthreads();              // conv(l-1) done with LDS
    fillLevel(l);
    __syncthreads();
    if (l == 0) convAcc(4, RLs[0] - 1);
    else        convAcc(3, RLs[l] - 1);
  }

  float* op = score + bc * 512 * 512;
  #pragma unroll
  for (int i = 0; i < 4; i++) {
    int Y = ty0 + oyl + i;
    float* orow = op + Y * 512 + tx0 + oxl;
    *(float4*)(orow)     = make_float4(acc[i][0], acc[i][1], acc[i][2], acc[i][3]);
    *(float4*)(orow + 4) = make_float4(acc[i][4], acc[i][5], acc[i][6], acc[i][7]);
  }
}

// ---------------- K6: 3x ft vertical pipeline, v3: 2 rows/iteration ----------------
// Barrier/latency-bound at ~930 cyc/iter wall vs ~150 cyc VALU -> amortize by
// processing TWO rows per barrier. Stagger becomes 7 (odd) so both consumed
// S-rows come from the PREVIOUS iteration (off = {0,7,14}; need
// off_{s+1} >= off_s + 7 with step 2). Rings r2/r3 = 12 rows = 6 iters ->
// unroll 6, all indices compile-time. brow: 2 rows per stage, double-buffered,
// ONE barrier per 2 rows (84 total vs 168). mstart = R0-15; masks generalize
// to (>= mstart-7) / (>= mstart-14); stores at i in [17,80] = rows R0..R0+127.
// Telescoping warm-up argument identical to verified v1/v2.
__global__ __launch_bounds__(256, 3) void k_ft_pipe(const float* __restrict__ s_in,
                                                    float* __restrict__ s_out,
                                                    const float* __restrict__ ft_gamma,
                                                    const float* __restrict__ ft_beta,
                                                    const float* __restrict__ ft_mean,
                                                    const float* __restrict__ ft_var,
                                                    const float* __restrict__ ft_k,
                                                    const float* __restrict__ ft_b,
                                                    const float* __restrict__ emph_w) {
  __shared__ float brow1[2][2][524];   // [buf][rowpair][col+6]; pads zeroed
  __shared__ float brow2[2][2][524];
  __shared__ float brow3[2][2][524];

  const int bc = blockIdx.y;          // 0..127
  const int c  = bc & 63;
  const int R0 = blockIdx.x << 7;     // band start row (0,128,256,384)
  const int mstart = R0 - 15;

  const float sc  = ft_gamma[c] * rsqrtf(ft_var[c] + 1e-5f);
  const float fk = *ft_k, fb = *ft_b;
  const float Aff = sc * fk;
  const float Cc  = (ft_beta[c] - ft_mean[c] * sc) * fk + fb;
  const float w   = emph_w[c];
  const float opw = 1.0f + w;
  const float okw = w * (1.0f / 121.0f);

  const int tid = threadIdx.x;
  const int x0  = tid << 1;

  const float* sp = s_in + ((size_t)bc << 18) + x0;
  float*       op = s_out + ((size_t)bc << 18) + x0;

  // zero horizontal pads: 3 arrays x 2 bufs x 2 rows x 12 elems = 144 threads
  if (tid < 144) {
    int a = tid / 48, rem = tid % 48;
    int pb = rem / 24, rw = (rem / 12) & 1, e = rem % 12;
    int idx = (e < 6) ? e : (512 + e);
    float* base = (a == 0) ? &brow1[pb][rw][0] : (a == 1) ? &brow2[pb][rw][0] : &brow3[pb][rw][0];
    base[idx] = 0.0f;
  }

  auto ldraw = [&](int row) -> v2f {
    int rc = min(max(row, 0), 511);        // clamp keeps the access in-bounds
    return *(const v2f*)(sp + ((size_t)rc << 9));
  };

  // two 11-sums (cols x0, x0+1) from brow window [x0-6 .. x0+7]
  auto rowsum = [&](const float* b) -> v2f {
    const float* p = b + x0;               // brow idx x0 == col x0-6
    v2f w0 = *(const v2f*)(p);
    v2f w1 = *(const v2f*)(p + 2);
    v2f w2 = *(const v2f*)(p + 4);
    v2f w3 = *(const v2f*)(p + 6);
    v2f w4 = *(const v2f*)(p + 8);
    v2f w5 = *(const v2f*)(p + 10);
    v2f w6 = *(const v2f*)(p + 12);
    float smid = ((w1.x + w1.y) + (w2.x + w2.y)) +
                 ((w3.x + w3.y) + (w4.x + w4.y)) + (w5.x + w5.y);   // cols x0-4..x0+5
    v2f r;
    r.x = smid + w0.y;   // + col x0-5
    r.y = smid + w6.x;   // + col x0+6
    return r;
  };

  v2f cs1 = (v2f)0.0f, cs2 = (v2f)0.0f, cs3 = (v2f)0.0f;
  v2f o1a = (v2f)0.0f, o1b = (v2f)0.0f;   // S1 rows m-5, m-4 of prev iter
  v2f o2a = (v2f)0.0f, o2b = (v2f)0.0f;   // S2 rows m-12, m-11 of prev iter

  v2f r2[12], r3[12];                  // register rings (compile-time indexed)
  #pragma unroll
  for (int k = 0; k < 12; k++) { r2[k] = (v2f)0.0f; r3[k] = (v2f)0.0f; }

  v2f gf0 = ldraw(mstart),      gf1 = ldraw(mstart + 1);   // fronts m, m+1
  v2f go0 = ldraw(mstart - 11), go1 = ldraw(mstart - 10);  // subs
  v2f gc0 = ldraw(mstart - 5),  gc1 = ldraw(mstart - 4);   // centers

  #pragma unroll 1
  for (int ii = 0; ii < 14; ++ii) {
    #pragma unroll
    for (int j = 0; j < 6; ++j) {
      const int i = ii * 6 + j;
      const int m = mstart + 2 * i;
      // prefetch next iteration's 6 rows (fronts are the only HBM-cold reads)
      v2f nf0 = ldraw(m + 2), nf1 = ldraw(m + 3);
      v2f no0 = ldraw(m - 9), no1 = ldraw(m - 8);
      v2f nc0 = ldraw(m - 3), nc1 = ldraw(m - 2);

      const int p = j & 1;

      // ---------------- W phase ----------------
      {  // stage 1: fronts m, m+1
        v2f u1fa = (m >= 0 && m < 512) ? (gf0 * Aff + Cc) : (v2f)0.0f;
        int ra = m - 11;
        v2f u1oa = (ra >= mstart && ra >= 0 && ra < 512) ? (go0 * Aff + Cc) : (v2f)0.0f;
        cs1 += u1fa - u1oa;                          // C1 at row m-5
        *(v2f*)(&brow1[p][0][6 + x0]) = cs1;
        v2f u1fb = (m + 1 >= 0 && m + 1 < 512) ? (gf1 * Aff + Cc) : (v2f)0.0f;
        int rb = m - 10;
        v2f u1ob = (rb >= mstart && rb >= 0 && rb < 512) ? (go1 * Aff + Cc) : (v2f)0.0f;
        cs1 += u1fb - u1ob;                          // C1 at row m-4
        *(v2f*)(&brow1[p][1][6 + x0]) = cs1;
      }
      {  // stage 2: fronts m-7 (o1a), m-6 (o1b); subs m-18, m-17
        v2f u2a = o1a * Aff + Cc;
        v2f u2b = o1b * Aff + Cc;
        v2f olda = r2[(2 * j + 1) % 12];             // row m-18 (read pre-write)
        v2f oldb = r2[(2 * j + 2) % 12];             // row m-17
        r2[2 * j] = u2a; r2[(2 * j + 1) % 12] = u2b;
        int rfa = m - 7, rsa = m - 18;
        v2f aadd = (rfa >= 0 && rfa < 512) ? u2a : (v2f)0.0f;
        v2f asub = (rsa >= mstart - 7 && rsa >= 0 && rsa < 512) ? olda : (v2f)0.0f;
        cs2 += aadd - asub;                          // C2 at row m-12
        *(v2f*)(&brow2[p][0][6 + x0]) = cs2;
        int rfb = m - 6, rsb = m - 17;
        v2f badd = (rfb >= 0 && rfb < 512) ? u2b : (v2f)0.0f;
        v2f bsub = (rsb >= mstart - 7 && rsb >= 0 && rsb < 512) ? oldb : (v2f)0.0f;
        cs2 += badd - bsub;                          // C2 at row m-11
        *(v2f*)(&brow2[p][1][6 + x0]) = cs2;
      }
      {  // stage 3: fronts m-14 (o2a), m-13 (o2b); subs m-25, m-24
        v2f u3a = o2a * Aff + Cc;
        v2f u3b = o2b * Aff + Cc;
        v2f olda = r3[(2 * j + 1) % 12];             // row m-25 (read pre-write)
        v2f oldb = r3[(2 * j + 2) % 12];             // row m-24
        r3[2 * j] = u3a; r3[(2 * j + 1) % 12] = u3b;
        int rfa = m - 14, rsa = m - 25;
        v2f aadd = (rfa >= 0 && rfa < 512) ? u3a : (v2f)0.0f;
        v2f asub = (rsa >= mstart - 14 && rsa >= 0 && rsa < 512) ? olda : (v2f)0.0f;
        cs3 += aadd - asub;                          // C3 at row m-19
        *(v2f*)(&brow3[p][0][6 + x0]) = cs3;
        int rfb = m - 13, rsb = m - 24;
        v2f badd = (rfb >= 0 && rfb < 512) ? u3b : (v2f)0.0f;
        v2f bsub = (rsb >= mstart - 14 && rsb >= 0 && rsb < 512) ? oldb : (v2f)0.0f;
        cs3 += badd - bsub;                          // C3 at row m-18
        *(v2f*)(&brow3[p][1][6 + x0]) = cs3;
      }
      __syncthreads();                               // brow[p] published
      // ---------------- R phase ----------------
      {  // S1 centers m-5, m-4
        int ra = m - 5, rb = m - 4;
        v2f u1ca = (ra >= 0 && ra < 512) ? (gc0 * Aff + Cc) : (v2f)0.0f;
        v2f u1cb = (rb >= 0 && rb < 512) ? (gc1 * Aff + Cc) : (v2f)0.0f;
        o1a = u1ca * opw - rowsum(&brow1[p][0][0]) * okw;
        o1b = u1cb * opw - rowsum(&brow1[p][1][0]) * okw;
      }
      {  // S2 centers m-12, m-11 (ring slots 2j+7, 2j+8)
        int ra = m - 12, rb = m - 11;
        v2f ua = r2[(2 * j + 7) % 12];
        v2f ub = r2[(2 * j + 8) % 12];
        v2f u2ca = (ra >= mstart - 7 && ra >= 0 && ra < 512) ? ua : (v2f)0.0f;
        v2f u2cb = (rb >= mstart - 7 && rb >= 0 && rb < 512) ? ub : (v2f)0.0f;
        o2a = u2ca * opw - rowsum(&brow2[p][0][0]) * okw;
        o2b = u2cb * opw - rowsum(&brow2[p][1][0]) * okw;
      }
      {  // S3 centers m-19, m-18 -> store
        int ra = m - 19, rb = m - 18;
        v2f ua = r3[(2 * j + 7) % 12];
        v2f ub = r3[(2 * j + 8) % 12];
        v2f u3ca = (ra >= mstart - 14 && ra >= 0 && ra < 512) ? ua : (v2f)0.0f;
        v2f u3cb = (rb >= mstart - 14 && rb >= 0 && rb < 512) ? ub : (v2f)0.0f;
        v2f oa = u3ca * opw - rowsum(&brow3[p][0][0]) * okw;
        v2f ob = u3cb * opw - rowsum(&brow3[p][1][0]) * okw;
        if (i >= 17 && i <= 80) {
          *(v2f*)(op + ((size_t)(m - 19) << 9)) = oa;   // rows R0..R0+126 (even)
          *(v2f*)(op + ((size_t)(m - 18) << 9)) = ob;   // rows R0+1..R0+127 (odd)
        }
      }
      // one barrier per iteration: next iter writes brow[p^1]; brow[p] is
      // rewritten two iters out, ordered after this R by the next barrier.
      gf0 = nf0; gf1 = nf1; go0 = no0; go1 = no1; gc0 = nc0; gc1 = nc1;
    }
  }
}

extern "C" void kernel_launch(void* const* d_in, const int* in_sizes, int n_in,
                              void* d_out, int out_size, void* d_ws, size_t ws_size,
                              hipStream_t stream) {
  const float* x        = (const float*)d_in[0];
  const float* w1       = (const float*)d_in[1];
  const float* b1       = (const float*)d_in[2];
  const float* w2       = (const float*)d_in[3];
  const float* b2       = (const float*)d_in[4];
  const float* down_k   = (const float*)d_in[5];
  const float* down_b   = (const float*)d_in[6];
  const float* ft_gamma = (const float*)d_in[7];
  const float* ft_beta  = (const float*)d_in[8];
  const float* ft_mean  = (const float*)d_in[9];
  const float* ft_var   = (const float*)d_in[10];
  const float* ft_k     = (const float*)d_in[11];
  const float* ft_b     = (const float*)d_in[12];
  const float* emph_w   = (const float*)d_in[13];
  const float* interp_k = (const float*)d_in[14];
  const float* interp_b = (const float*)d_in[15];
  const float* i_gamma  = (const float*)d_in[16];
  const float* i_beta   = (const float*)d_in[17];
  const float* i_mean   = (const float*)d_in[18];
  const float* i_var    = (const float*)d_in[19];
  float* out = (float*)d_out;                    // [2,64,512,512]

  char* ws = (char*)d_ws;
  size_t off = 0;
  auto alloc = [&](size_t bytes) { size_t r = off; off += (bytes + 255) & ~(size_t)255; return r; };
  unsigned char* hmode = (unsigned char*)(ws + alloc((size_t)NB * CIN * HM * HM));
  float* d1 = (float*)(ws + alloc((size_t)NB * C2 * 168 * 168 * 4));
  float* d2 = (float*)(ws + alloc((size_t)NB * C2 * 56 * 56 * 4));
  float* d3 = (float*)(ws + alloc((size_t)NB * C2 * 19 * 19 * 4));
  float* d4 = (float*)(ws + alloc((size_t)NB * C2 * 7 * 7 * 4));
  float* d5 = (float*)(ws + alloc((size_t)NB * C2 * 3 * 3 * 4));
  float* s0 = (float*)(ws + alloc((size_t)NB * C2 * 512 * 512 * 4));  // pre-ft score
  float2* lutpk = (float2*)(ws + alloc((size_t)5 * 512 * 8));

  k_mode<<<dim3(32, 32, NB * CIN), 256, 0, stream>>>(x, hmode);
  k_lut<<<10, 256, 0, stream>>>(lutpk);
  k_prepare<<<dim3((168 * 168 + 255) / 256, NB * C2), 256, 0, stream>>>(
      hmode, w1, b1, w2, b2, down_k, down_b, d1);
  k_down<<<dim3((56 * 56 + 255) / 256, NB * C2), 256, 0, stream>>>(d1, d2, down_k, down_b, 168, 56);
  k_down<<<dim3((19 * 19 + 255) / 256, NB * C2), 256, 0, stream>>>(d2, d3, down_k, down_b, 56, 19);
  k_down<<<dim3((7 * 7 + 255) / 256, NB * C2), 256, 0, stream>>>(d3, d4, down_k, down_b, 19, 7);
  k_down<<<dim3((3 * 3 + 255) / 256, NB * C2), 256, 0, stream>>>(d4, d5, down_k, down_b, 7, 3);
  k_score<<<dim3(32, NB * C2), 256, 0, stream>>>(d1, d2, d3, d4, d5, lutpk,
                                                 interp_k, interp_b,
                                                 i_gamma, i_beta, i_mean, i_var, s0);
  k_ft_pipe<<<dim3(4, NB * C2), 256, 0, stream>>>(s0, out, ft_gamma, ft_beta, ft_mean,
                                                  ft_var, ft_k, ft_b, emph_w);
}

// Round 8
// 542.037 us; speedup vs baseline: 1.0068x; 1.0068x over previous
//
#include <hip/hip_runtime.h>

#define NB 2
#define CIN 3
#define HH 512
#define WW 512
#define C2 64
#define HM 504   // mode-pool output size

typedef float v2f  __attribute__((ext_vector_type(2)));
typedef float v2fu __attribute__((ext_vector_type(2), aligned(4)));

// ---------------- K2: quantize (inline) + mode pool 11x11 -> u8 [2,3,504,504] ----------------
__global__ __launch_bounds__(256) void k_mode(const float* __restrict__ x,
                                              unsigned char* __restrict__ hmode) {
  __shared__ unsigned char tile[26 * 26];
  int bc  = blockIdx.z;
  int ty0 = blockIdx.y * 16, tx0 = blockIdx.x * 16;
  const float* src = x + (size_t)bc * HH * WW;
  for (int i = threadIdx.x; i < 26 * 26; i += 256) {
    int r = i / 26, cl = i % 26;
    int Y = ty0 + r, X = tx0 + cl;      // padded coords (pad=1)
    unsigned char v = 0;
    if (Y >= 1 && Y <= HH && X >= 1 && X <= WW) {
      float val = src[(Y - 1) * WW + (X - 1)];
      float q = rintf((val * 255.0f) / 16.0f);   // matches jnp.round(x*255/16), RNE
      q = fminf(fmaxf(q, 0.0f), 16.0f);
      v = (unsigned char)(int)q;
    }
    tile[i] = v;
  }
  __syncthreads();
  int ty = threadIdx.x >> 4, tx = threadIdx.x & 15;
  int oy = ty0 + ty, ox = tx0 + tx;
  if (oy >= HM || ox >= HM) return;
  unsigned long long w0 = 0, w1 = 0, w2 = 0;
  for (int dy = 0; dy < 11; dy++) {
    #pragma unroll
    for (int dx = 0; dx < 11; dx++) {
      int b = tile[(ty + dy) * 26 + tx + dx];
      unsigned long long inc = 1ull << ((b & 7) * 8);
      if (b < 8) w0 += inc;
      else if (b < 16) w1 += inc;
      else w2 += inc;
    }
  }
  int best = -1, bestb = 0;
  #pragma unroll
  for (int b = 0; b < 17; b++) {
    int cnt;
    if (b < 8)       cnt = (int)((w0 >> (b * 8)) & 0xff);
    else if (b < 16) cnt = (int)((w1 >> ((b - 8) * 8)) & 0xff);
    else             cnt = (int)(w2 & 0xff);
    if (cnt > best) { best = cnt; bestb = b; }   // strict > keeps lowest bin on tie
  }
  hmode[bc * HM * HM + oy * HM + ox] = (unsigned char)bestb;
}

// ---------------- K3: fused conv1+maxleaky + grouped conv2 + minleaky + downgrade ----------------
__global__ __launch_bounds__(256) void k_prepare(const unsigned char* __restrict__ hmode,
                                                 const float* __restrict__ w1,
                                                 const float* __restrict__ b1,
                                                 const float* __restrict__ w2,
                                                 const float* __restrict__ b2,
                                                 const float* __restrict__ down_k,
                                                 const float* __restrict__ down_b,
                                                 float* __restrict__ d1) {
  int bc = blockIdx.y;
  int b  = bc >> 6;
  int c  = bc & 63;
  int pix = blockIdx.x * 256 + threadIdx.x;
  if (pix >= 168 * 168) return;
  int oy = pix / 168, ox = pix % 168;
  int c0 = (c >> 1) << 1;
  float w1a0 = w1[c0 * 3], w1a1 = w1[c0 * 3 + 1], w1a2 = w1[c0 * 3 + 2], b1a = b1[c0];
  float w1b0 = w1[(c0 + 1) * 3], w1b1 = w1[(c0 + 1) * 3 + 1], w1b2 = w1[(c0 + 1) * 3 + 2], b1b = b1[c0 + 1];
  float w2a = w2[c * 2], w2b = w2[c * 2 + 1], b2c = b2[c];
  float kb = *down_b;
  const unsigned char* h0p = hmode + (b * 3 + 0) * HM * HM;
  const unsigned char* h1p = hmode + (b * 3 + 1) * HM * HM;
  const unsigned char* h2p = hmode + (b * 3 + 2) * HM * HM;
  float acc = 0.0f;
  #pragma unroll
  for (int ky = 0; ky < 3; ky++) {
    int y = 3 * oy - 1 + ky;
    if (y < 0 || y >= HM) continue;
    #pragma unroll
    for (int kx = 0; kx < 3; kx++) {
      int xx = 3 * ox - 1 + kx;
      if (xx < 0 || xx >= HM) continue;
      int o = y * HM + xx;
      float hh0 = h0p[o] * (1.0f / 16.0f);
      float hh1 = h1p[o] * (1.0f / 16.0f);
      float hh2 = h2p[o] * (1.0f / 16.0f);
      float a0 = w1a0 * hh0 + w1a1 * hh1 + w1a2 * hh2 + b1a;
      float a1 = w1b0 * hh0 + w1b1 * hh1 + w1b2 * hh2 + b1b;
      a0 = (a0 <= 0.1f) ? a0 : 0.1f + 0.01f * (a0 - 0.1f);
      a1 = (a1 <= 0.1f) ? a1 : 0.1f + 0.01f * (a1 - 0.1f);
      float v = w2a * a0 + w2b * a1 + b2c;
      v = (v >= 0.1f) ? v : 0.1f + 0.01f * (v - 0.1f);
      acc += down_k[ky * 3 + kx] * v;
    }
  }
  float r = acc + kb;
  r = (r >= 0.0f) ? r : 0.01f * r;
  d1[bc * 168 * 168 + pix] = r;
}

// ---------------- K4: generic downgrade (3x3 s3 p1 shared) + leaky ----------------
__global__ __launch_bounds__(256) void k_down(const float* __restrict__ din,
                                              float* __restrict__ dout,
                                              const float* __restrict__ down_k,
                                              const float* __restrict__ down_b,
                                              int S, int So) {
  int bc = blockIdx.y;
  int pix = blockIdx.x * 256 + threadIdx.x;
  if (pix >= So * So) return;
  int oy = pix / So, ox = pix % So;
  const float* p = din + bc * S * S;
  float acc = 0.0f;
  #pragma unroll
  for (int ky = 0; ky < 3; ky++) {
    int y = 3 * oy - 1 + ky;
    if (y < 0 || y >= S) continue;
    #pragma unroll
    for (int kx = 0; kx < 3; kx++) {
      int xx = 3 * ox - 1 + kx;
      if (xx < 0 || xx >= S) continue;
      acc += down_k[ky * 3 + kx] * p[y * S + xx];
    }
  }
  float r = acc + *down_b;
  r = (r >= 0.0f) ? r : 0.01f * r;
  dout[bc * So * So + pix] = r;
}

// ---------------- K_lut: packed bilinear LUT {asfloat(y0), w} per level/coord ----------------
__global__ __launch_bounds__(256) void k_lut(float2* __restrict__ lutpk) {
  int idx = blockIdx.x * 256 + threadIdx.x;   // 5*512
  if (idx >= 5 * 512) return;
  int lvl = idx >> 9, Y = idx & 511;
  const int Ls[5] = {168, 56, 19, 7, 3};
  int L = Ls[lvl];
  float f = (Y + 0.5f) * ((float)L / 512.0f) - 0.5f;
  f = fminf(fmaxf(f, 0.0f), (float)(L - 1));
  int y0 = (int)f;
  float w = f - (float)y0;
  lutpk[idx] = make_float2(__int_as_float(y0), w);
}

// ---------------- K5: composite 5-level resize+conv+BN+leaky+sum, v4 ----------------
// v4: loop-swap in convAcc. The union of coarse rows needed by a thread's 4
// output rows is the interval [ab0, ab3+rspan) (abase monotone in y) — 4-6
// rows vs the 12-16 (row,tap) reads of v3. Each row's 12-dword window is read
// ONCE and scattered into all (i, rr=g-ab[i]) accumulators with range
// predication; the (i,rr,row,kap) pair set is identical to v3 -> bit-identical
// math. Cuts xrow LDS traffic ~2.6x (the v3 bottleneck: ~49us wave-throughput
// + ~31us conflicts; the R7 pad experiment showed conflicts are cross-group
// row aliasing, unfixable by static padding -> fix by reading less).
#define XI(cc) ((cc) + ((((cc) >> 5)) << 2))
#define XSTR 148
__global__ __launch_bounds__(256, 4) void k_score(const float* __restrict__ d1,
                                                  const float* __restrict__ d2,
                                                  const float* __restrict__ d3,
                                                  const float* __restrict__ d4,
                                                  const float* __restrict__ d5,
                                                  const float2* __restrict__ lutpk,
                                                  const float* __restrict__ interp_k,
                                                  const float* __restrict__ interp_b,
                                                  const float* __restrict__ i_gamma,
                                                  const float* __restrict__ i_beta,
                                                  const float* __restrict__ i_mean,
                                                  const float* __restrict__ i_var,
                                                  float* __restrict__ score) {
  __shared__ float xrow[24 * XSTR];    // [r][XI(xx)]
  __shared__ float kap[64 * 36];       // [y][rr*8 + kx], 5 used per slot
  __shared__ int   abase[64];          // a0base(y) - r0

  int bc = blockIdx.y;
  int c  = bc & 63;
  int tile = blockIdx.x;               // 32 tiles: 8 y-tiles x 4 x-tiles
  int tyi = tile >> 2, txi = tile & 3;
  int ty0 = tyi * 64, tx0 = txi * 128;
  float K[25];
  #pragma unroll
  for (int i = 0; i < 25; i++)
    K[i] = __int_as_float(__builtin_amdgcn_readfirstlane(__float_as_int(interp_k[i])));
  float ib  = __int_as_float(__builtin_amdgcn_readfirstlane(__float_as_int(*interp_b)));
  float isc = i_gamma[c] * rsqrtf(i_var[c] + 1e-5f);
  float ibe = i_beta[c] - i_mean[c] * isc;
  int tid = threadIdx.x;
  int oyl = (tid >> 4) << 2, oxl = (tid & 15) << 3;  // 4x8 px per thread
  const int pA = XI(oxl);              // col oxl   (A; B = pA+4)
  const int pC = XI(oxl + 8);          // col oxl+8 (Cx)
  float acc[4][8];
  #pragma unroll
  for (int i = 0; i < 4; i++)
    #pragma unroll
    for (int j = 0; j < 8; j++) acc[i][j] = 0.0f;

  const float* dls[5] = {d1, d2, d3, d4, d5};
  const int Ls[5]  = {168, 56, 19, 7, 3};
  const int RLs[5] = {24, 10, 5, 3, 3};

  auto fillLevel = [&](int l) {
    int L = Ls[l], RR = RLs[l];
    const float* dp = dls[l] + bc * L * L;
    const float2* lp = lutpk + (l << 9);
    int Ylo = max(ty0 - 2, 0);
    int r0 = __float_as_int(lp[Ylo].x);
    // kappa: thread tid -> (y = tid>>2, rrel = tid&3)
    {
      int y = tid >> 2, rr = tid & 3;
      int Y = ty0 + y;
      float kv0 = 0.0f, kv1 = 0.0f, kv2 = 0.0f, kv3 = 0.0f, kv4 = 0.0f;
      int ab = -1;
      #pragma unroll
      for (int ky = 0; ky < 5; ky++) {
        int yy = Y + ky - 2;
        if (yy >= 0 && yy < 512) {
          float2 pk = lp[yy];
          int a0 = __float_as_int(pk.x);
          float wv = pk.y;
          if (ab < 0) ab = a0;           // first valid ky has the min a0 (monotone)
          float cf = 0.0f;
          if (a0 - ab == rr)     cf += 1.0f - wv;
          if (a0 + 1 - ab == rr) cf += wv;
          kv0 += cf * K[ky * 5 + 0];
          kv1 += cf * K[ky * 5 + 1];
          kv2 += cf * K[ky * 5 + 2];
          kv3 += cf * K[ky * 5 + 3];
          kv4 += cf * K[ky * 5 + 4];
        }
      }
      float* kp = &kap[y * 36 + rr * 8];
      kp[0] = kv0; kp[1] = kv1; kp[2] = kv2; kp[3] = kv3; kp[4] = kv4;
      if (rr == 0) abase[y] = ab - r0;
    }
    // xrow: x-upsample coarse rows, zero outside image columns
    for (int i = tid; i < RR * 132; i += 256) {
      int r = i / 132, xx = i - r * 132;
      int X = tx0 - 2 + xx;
      float v = 0.0f;
      if (X >= 0 && X < 512) {
        float2 pk = lp[X];
        int ix = __float_as_int(pk.x);
        float wx = pk.y;
        int gr = min(r0 + r, L - 1);
        const float* rp = dp + gr * L + ix;
        float v0 = rp[0], v1 = rp[1];    // v1 unused when wx==0 (clamp)
        v = v0 + wx * (v1 - v0);
      }
      xrow[r * XSTR + XI(xx)] = v;
    }
  };

  auto convAcc = [&](int rspan, int rlim) {
    int ab0 = abase[oyl];
    int ab1 = abase[oyl + 1];
    int ab2 = abase[oyl + 2];
    int ab3 = abase[oyl + 3];
    float t[4][8];
    #pragma unroll
    for (int i = 0; i < 4; i++)
      #pragma unroll
      for (int j = 0; j < 8; j++) t[i][j] = 0.0f;
    int gend = ab3 + rspan;              // exclusive; abase monotone so union = [ab0, gend)
    for (int g = ab0; g < gend; ++g) {
      int row = min(g, rlim);            // kappa==0 whenever clamp engages
      const float* xp = &xrow[row * XSTR];
      float4 A = *(const float4*)(xp + pA);
      float4 B = *(const float4*)(xp + pA + 4);
      float4 Cx = *(const float4*)(xp + pC);
      float wnd[12] = {A.x, A.y, A.z, A.w, B.x, B.y, B.z, B.w, Cx.x, Cx.y, Cx.z, Cx.w};
      int abv[4] = {ab0, ab1, ab2, ab3};
      #pragma unroll
      for (int i = 0; i < 4; i++) {
        int rr = g - abv[i];
        if (rr >= 0 && rr < rspan) {
          const float* kp = &kap[(oyl + i) * 36 + rr * 8];
          float4 kk = *(const float4*)kp;
          float k4v = kp[4];
          #pragma unroll
          for (int j = 0; j < 8; j++)
            t[i][j] += kk.x * wnd[j] + kk.y * wnd[j + 1] + kk.z * wnd[j + 2] +
                       kk.w * wnd[j + 3] + k4v * wnd[j + 4];
        }
      }
    }
    #pragma unroll
    for (int i = 0; i < 4; i++)
      #pragma unroll
      for (int j = 0; j < 8; j++) {
        float v = (t[i][j] + ib) * isc + ibe;
        v = (v >= 0.0f) ? v : 0.01f * v;
        acc[i][j] += v;
      }
  };

  #pragma unroll 1
  for (int l = 0; l < 5; l++) {
    if (l) __syncthreads();              // conv(l-1) done with LDS
    fillLevel(l);
    __syncthreads();
    if (l == 0) convAcc(4, RLs[0] - 1);
    else        convAcc(3, RLs[l] - 1);
  }

  float* op = score + bc * 512 * 512;
  #pragma unroll
  for (int i = 0; i < 4; i++) {
    int Y = ty0 + oyl + i;
    float* orow = op + Y * 512 + tx0 + oxl;
    *(float4*)(orow)     = make_float4(acc[i][0], acc[i][1], acc[i][2], acc[i][3]);
    *(float4*)(orow + 4) = make_float4(acc[i][4], acc[i][5], acc[i][6], acc[i][7]);
  }
}

// ---------------- K6: 3x ft vertical pipeline, v2 (reverted from v3: the
// 2-rows/iter variant regressed ~15us in R7; v2 is the measured-good form) ----------------
__global__ __launch_bounds__(256, 3) void k_ft_pipe(const float* __restrict__ s_in,
                                                    float* __restrict__ s_out,
                                                    const float* __restrict__ ft_gamma,
                                                    const float* __restrict__ ft_beta,
                                                    const float* __restrict__ ft_mean,
                                                    const float* __restrict__ ft_var,
                                                    const float* __restrict__ ft_k,
                                                    const float* __restrict__ ft_b,
                                                    const float* __restrict__ emph_w) {
  __shared__ float brow1[2][524];     // col c at idx c+6; pads [0..5],[518..523] = 0
  __shared__ float brow2[2][524];
  __shared__ float brow3[2][524];

  const int bc = blockIdx.y;          // 0..127
  const int c  = bc & 63;
  const int R0 = blockIdx.x << 7;     // band start row (0,128,256,384)
  const int mstart = R0 - 15;

  const float sc  = ft_gamma[c] * rsqrtf(ft_var[c] + 1e-5f);
  const float fk = *ft_k, fb = *ft_b;
  const float Aff = sc * fk;
  const float Cc  = (ft_beta[c] - ft_mean[c] * sc) * fk + fb;
  const float w   = emph_w[c];
  const float opw = 1.0f + w;
  const float okw = w * (1.0f / 121.0f);

  const int tid = threadIdx.x;
  const int x0  = tid << 1;

  const float* sp = s_in + ((size_t)bc << 18) + x0;
  float*       op = s_out + ((size_t)bc << 18) + x0;

  // zero the horizontal pads (both buffers); ordered before first read by the
  // first in-loop barrier
  if (tid < 72) {
    int a = tid / 24, pb = (tid / 12) & 1, e = tid % 12;
    int idx = (e < 6) ? e : (512 + e);
    float* base = (a == 0) ? &brow1[pb][0] : (a == 1) ? &brow2[pb][0] : &brow3[pb][0];
    base[idx] = 0.0f;
  }

  auto ldraw = [&](int row) -> v2f {
    int rc = min(max(row, 0), 511);        // clamp keeps the access in-bounds
    return *(const v2f*)(sp + ((size_t)rc << 9));
  };

  // two 11-sums (cols x0, x0+1) from brow window [x0-6 .. x0+7]
  auto rowsum = [&](const float* b) -> v2f {
    const float* p = b + x0;               // brow idx x0 == col x0-6
    v2f w0 = *(const v2f*)(p);
    v2f w1 = *(const v2f*)(p + 2);
    v2f w2 = *(const v2f*)(p + 4);
    v2f w3 = *(const v2f*)(p + 6);
    v2f w4 = *(const v2f*)(p + 8);
    v2f w5 = *(const v2f*)(p + 10);
    v2f w6 = *(const v2f*)(p + 12);
    float smid = ((w1.x + w1.y) + (w2.x + w2.y)) +
                 ((w3.x + w3.y) + (w4.x + w4.y)) + (w5.x + w5.y);   // cols x0-4..x0+5
    v2f r;
    r.x = smid + w0.y;   // + col x0-5
    r.y = smid + w6.x;   // + col x0+6
    return r;
  };

  v2f cs1 = (v2f)0.0f, cs2 = (v2f)0.0f, cs3 = (v2f)0.0f;
  v2f out1p = (v2f)0.0f, out2p = (v2f)0.0f;   // S1/S2 rows produced last step (raw)

  v2f r2[12], r3[12];                  // register rings (compile-time indexed)
  #pragma unroll
  for (int k = 0; k < 12; k++) { r2[k] = (v2f)0.0f; r3[k] = (v2f)0.0f; }

  v2f gf  = ldraw(mstart);            // row m       (stage-1 front)
  v2f gfa = ldraw(mstart + 1);        // row m+1     (front prefetch, depth 2)
  v2f go  = ldraw(mstart - 11);       // row m-11    (stage-1 subtract, L2-hot)
  v2f gc  = ldraw(mstart - 5);        // row m-5     (stage-1 center, L2-hot)

  #pragma unroll 1
  for (int ii = 0; ii < 14; ++ii) {
    #pragma unroll
    for (int j = 0; j < 12; ++j) {
      const int i = ii * 12 + j;
      const int m = mstart + i;
      // prefetch: front 2-deep (HBM-cold), others 1-deep (L2-hot re-reads)
      v2f gf_n2 = ldraw(m + 2);
      v2f go_n  = ldraw(m - 10);
      v2f gc_n  = ldraw(m - 4);

      const int p = j & 1;

      // ---------------- W phase: advance column sums, publish C rows ----------------
      {  // stage 1: front row m
        v2f u1f = (m >= 0 && m < 512) ? (gf * Aff + Cc) : (v2f)0.0f;
        int r = m - 11;
        v2f u1o = (r >= mstart && r >= 0 && r < 512) ? (go * Aff + Cc) : (v2f)0.0f;
        cs1 += u1f - u1o;                            // cs1 = colsum at row m-5
        *(v2f*)(&brow1[p][6 + x0]) = cs1;
      }
      {  // stage 2: front row m-6 (consumes out1p = S1(m-6))
        v2f u2s = out1p * Aff + Cc;
        v2f u2or = r2[(j + 1) % 12];                 // value from 11 iters ago
        r2[j] = u2s;
        int rf = m - 6;
        v2f u2f = (rf >= 0 && rf < 512) ? u2s : (v2f)0.0f;
        int r = m - 17;
        v2f u2o = (r >= mstart - 6 && r >= 0 && r < 512) ? u2or : (v2f)0.0f;
        cs2 += u2f - u2o;                            // cs2 = colsum at row m-11
        *(v2f*)(&brow2[p][6 + x0]) = cs2;
      }
      {  // stage 3: front row m-12 (consumes out2p = S2(m-12))
        v2f u3s = out2p * Aff + Cc;
        v2f u3or = r3[(j + 1) % 12];
        r3[j] = u3s;
        int rf = m - 12;
        v2f u3f = (rf >= 0 && rf < 512) ? u3s : (v2f)0.0f;
        int r = m - 23;
        v2f u3o = (r >= mstart - 12 && r >= 0 && r < 512) ? u3or : (v2f)0.0f;
        cs3 += u3f - u3o;                            // cs3 = colsum at row m-17
        *(v2f*)(&brow3[p][6 + x0]) = cs3;
      }
      __syncthreads();                               // brow[p] published
      // ---------------- R phase: horizontal 11-sums, emit stage outputs ----------------
      {  // S1(m-5)
        int rc1 = m - 5;
        v2f u1c = (rc1 >= 0 && rc1 < 512) ? (gc * Aff + Cc) : (v2f)0.0f;
        v2f B1 = rowsum(&brow1[p][0]);
        out1p = u1c * opw - B1 * okw;
      }
      {  // S2(m-11)
        int rc2 = m - 11;
        v2f u2cr = r2[(j + 7) % 12];                 // value from 5 iters ago
        v2f u2c = (rc2 >= mstart - 6 && rc2 >= 0 && rc2 < 512) ? u2cr : (v2f)0.0f;
        v2f B2 = rowsum(&brow2[p][0]);
        out2p = u2c * opw - B2 * okw;
      }
      {  // S3(m-17) -> global
        int rc3 = m - 17;
        v2f u3cr = r3[(j + 7) % 12];
        v2f u3c = (rc3 >= mstart - 12 && rc3 >= 0 && rc3 < 512) ? u3cr : (v2f)0.0f;
        v2f B3 = rowsum(&brow3[p][0]);
        v2f o3 = u3c * opw - B3 * okw;
        if (i >= 32 && i < 160)
          *(v2f*)(op + ((size_t)(m - 17) << 9)) = o3;   // rows R0 .. R0+127
      }
      // no second barrier: next iter writes brow[p^1]; brow[p] is rewritten
      // two iters from now, ordered after this R by the next iter's barrier.
      gf = gfa; gfa = gf_n2; go = go_n; gc = gc_n;
    }
  }
}

extern "C" void kernel_launch(void* const* d_in, const int* in_sizes, int n_in,
                              void* d_out, int out_size, void* d_ws, size_t ws_size,
                              hipStream_t stream) {
  const float* x        = (const float*)d_in[0];
  const float* w1       = (const float*)d_in[1];
  const float* b1       = (const float*)d_in[2];
  const float* w2       = (const float*)d_in[3];
  const float* b2       = (const float*)d_in[4];
  const float* down_k   = (const float*)d_in[5];
  const float* down_b   = (const float*)d_in[6];
  const float* ft_gamma = (const float*)d_in[7];
  const float* ft_beta  = (const float*)d_in[8];
  const float* ft_mean  = (const float*)d_in[9];
  const float* ft_var   = (const float*)d_in[10];
  const float* ft_k     = (const float*)d_in[11];
  const float* ft_b     = (const float*)d_in[12];
  const float* emph_w   = (const float*)d_in[13];
  const float* interp_k = (const float*)d_in[14];
  const float* interp_b = (const float*)d_in[15];
  const float* i_gamma  = (const float*)d_in[16];
  const float* i_beta   = (const float*)d_in[17];
  const float* i_mean   = (const float*)d_in[18];
  const float* i_var    = (const float*)d_in[19];
  float* out = (float*)d_out;                    // [2,64,512,512]

  char* ws = (char*)d_ws;
  size_t off = 0;
  auto alloc = [&](size_t bytes) { size_t r = off; off += (bytes + 255) & ~(size_t)255; return r; };
  unsigned char* hmode = (unsigned char*)(ws + alloc((size_t)NB * CIN * HM * HM));
  float* d1 = (float*)(ws + alloc((size_t)NB * C2 * 168 * 168 * 4));
  float* d2 = (float*)(ws + alloc((size_t)NB * C2 * 56 * 56 * 4));
  float* d3 = (float*)(ws + alloc((size_t)NB * C2 * 19 * 19 * 4));
  float* d4 = (float*)(ws + alloc((size_t)NB * C2 * 7 * 7 * 4));
  float* d5 = (float*)(ws + alloc((size_t)NB * C2 * 3 * 3 * 4));
  float* s0 = (float*)(ws + alloc((size_t)NB * C2 * 512 * 512 * 4));  // pre-ft score
  float2* lutpk = (float2*)(ws + alloc((size_t)5 * 512 * 8));

  k_mode<<<dim3(32, 32, NB * CIN), 256, 0, stream>>>(x, hmode);
  k_lut<<<10, 256, 0, stream>>>(lutpk);
  k_prepare<<<dim3((168 * 168 + 255) / 256, NB * C2), 256, 0, stream>>>(
      hmode, w1, b1, w2, b2, down_k, down_b, d1);
  k_down<<<dim3((56 * 56 + 255) / 256, NB * C2), 256, 0, stream>>>(d1, d2, down_k, down_b, 168, 56);
  k_down<<<dim3((19 * 19 + 255) / 256, NB * C2), 256, 0, stream>>>(d2, d3, down_k, down_b, 56, 19);
  k_down<<<dim3((7 * 7 + 255) / 256, NB * C2), 256, 0, stream>>>(d3, d4, down_k, down_b, 19, 7);
  k_down<<<dim3((3 * 3 + 255) / 256, NB * C2), 256, 0, stream>>>(d4, d5, down_k, down_b, 7, 3);
  k_score<<<dim3(32, NB * C2), 256, 0, stream>>>(d1, d2, d3, d4, d5, lutpk,
                                                 interp_k, interp_b,
                                                 i_gamma, i_beta, i_mean, i_var, s0);
  k_ft_pipe<<<dim3(4, NB * C2), 256, 0, stream>>>(s0, out, ft_gamma, ft_beta, ft_mean,
                                                  ft_var, ft_k, ft_b, emph_w);
}